// Round 1
// baseline (761.268 us; speedup 1.0000x reference)
//
#include <hip/hip_runtime.h>
#include <hip/hip_bf16.h>

#define NROWS 1000000
#define DIM 128
#define NSEG 16384
#define TILE_M 32
#define NT (NROWS / TILE_M)      // 31250 tiles
#define XH_STRIDE 136            // bf16 elems per row (128 + 8 pad)
#define HB_STRIDE (TILE_M + 1)   // 33 floats (odd -> conflict-free column scan)
#define GRID1 2048
#define EPSV 1e-5f

typedef __bf16 bf16x8 __attribute__((ext_vector_type(8)));
typedef __bf16 bf16x4 __attribute__((ext_vector_type(4)));
typedef float  f32x4  __attribute__((ext_vector_type(4)));

__global__ __launch_bounds__(256, 2)
void fused_lin_ln_scatter(const float* __restrict__ x,
                          const int*   __restrict__ batch,
                          const float* __restrict__ W,
                          const float* __restrict__ bias,
                          const float* __restrict__ lnw,
                          const float* __restrict__ lnb,
                          float* __restrict__ out) {
    __shared__ __align__(16) __bf16 xh[TILE_M * XH_STRIDE];
    __shared__ float  hbuf[DIM * HB_STRIDE];
    __shared__ float2 stat2[2][TILE_M];
    __shared__ int    ibuf[TILE_M];

    const int t    = threadIdx.x;
    const int wave = t >> 6;
    const int lane = t & 63;
    const int q    = lane >> 4;     // quad within wave
    const int l15  = lane & 15;
    const int rg   = wave >> 1;     // row group (0/1): rows rg*16..+16
    const int fh   = wave & 1;      // feature half (0/1)
    const int fbase = fh * 64;

    // ---- W fragments to registers (bf16 hi+lo), once per block ----
    // B^T layout: lane needs W[n = fbase+nt*16+l15][k = ks*32 + q*8 + j]
    bf16x8 whf[4][4], wlf[4][4];
    #pragma unroll
    for (int nt = 0; nt < 4; ++nt) {
        const int f = fbase + nt * 16 + l15;
        #pragma unroll
        for (int ks = 0; ks < 4; ++ks) {
            const int k0 = ks * 32 + q * 8;
            const float4* wp = (const float4*)(W + f * DIM + k0);
            float4 a = wp[0], c = wp[1];
            float wv[8] = {a.x, a.y, a.z, a.w, c.x, c.y, c.z, c.w};
            bf16x8 hi, lo;
            #pragma unroll
            for (int j = 0; j < 8; ++j) {
                __bf16 h = (__bf16)wv[j];
                hi[j] = h;
                lo[j] = (__bf16)(wv[j] - (float)h);
            }
            whf[nt][ks] = hi;
            wlf[nt][ks] = lo;
        }
    }
    float bb[4], lwv[4], lbv[4];
    #pragma unroll
    for (int nt = 0; nt < 4; ++nt) {
        const int f = fbase + nt * 16 + l15;
        bb[nt] = bias[f];
        lwv[nt] = lnw[f];
        lbv[nt] = lnb[f];
    }

    // ---- prologue: prefetch first tile into registers ----
    int it = blockIdx.x;
    float4 xr[4];
    int ibv = 0;
    {
        const float4* xp = (const float4*)(x + (size_t)it * TILE_M * DIM);
        #pragma unroll
        for (int j = 0; j < 4; ++j) xr[j] = xp[t + 256 * j];
        if (t < TILE_M) ibv = batch[it * TILE_M + t];
    }

    for (; it < NT; it += GRID1) {
        // 1: stage current tile (fp32 regs -> bf16 LDS), write segment ids
        #pragma unroll
        for (int j = 0; j < 4; ++j) {
            const int idx = t + 256 * j;
            const int row = idx >> 5;
            const int c4  = (idx & 31) * 4;
            float4 v = xr[j];
            bf16x4 pk = {(__bf16)v.x, (__bf16)v.y, (__bf16)v.z, (__bf16)v.w};
            *(bf16x4*)&xh[row * XH_STRIDE + c4] = pk;
        }
        if (t < TILE_M) ibuf[t] = ibv;
        __syncthreads();   // B0: xh + ibuf visible

        // 2: prefetch next tile into registers (latency hides under MFMA)
        const int itn = it + GRID1;
        if (itn < NT) {
            const float4* xp = (const float4*)(x + (size_t)itn * TILE_M * DIM);
            #pragma unroll
            for (int j = 0; j < 4; ++j) xr[j] = xp[t + 256 * j];
            if (t < TILE_M) ibv = batch[itn * TILE_M + t];
        }

        // 3: MFMA — 16 rows x 64 feats per wave, K=128, 2 passes (wh, wl)
        f32x4 acc[4];
        #pragma unroll
        for (int nt = 0; nt < 4; ++nt) acc[nt] = (f32x4){0.f, 0.f, 0.f, 0.f};
        const int row_l = rg * 16 + l15;
        #pragma unroll
        for (int ks = 0; ks < 4; ++ks) {
            bf16x8 af = *(const bf16x8*)&xh[row_l * XH_STRIDE + ks * 32 + q * 8];
            #pragma unroll
            for (int nt = 0; nt < 4; ++nt) {
                acc[nt] = __builtin_amdgcn_mfma_f32_16x16x32_bf16(af, whf[nt][ks], acc[nt], 0, 0, 0);
                acc[nt] = __builtin_amdgcn_mfma_f32_16x16x32_bf16(af, wlf[nt][ks], acc[nt], 0, 0, 0);
            }
        }

        // 4: row stats over this wave's 64 features (16-lane butterfly)
        float s[4], sq[4];
        #pragma unroll
        for (int r = 0; r < 4; ++r) {
            float a0 = acc[0][r] + bb[0], a1 = acc[1][r] + bb[1];
            float a2 = acc[2][r] + bb[2], a3 = acc[3][r] + bb[3];
            s[r]  = a0 + a1 + a2 + a3;
            sq[r] = a0 * a0 + a1 * a1 + a2 * a2 + a3 * a3;
            #pragma unroll
            for (int m = 1; m < 16; m <<= 1) {
                s[r]  += __shfl_xor(s[r],  m, 64);
                sq[r] += __shfl_xor(sq[r], m, 64);
            }
        }
        if (l15 == 0) {
            #pragma unroll
            for (int r = 0; r < 4; ++r)
                stat2[fh][rg * 16 + q * 4 + r] = make_float2(s[r], sq[r]);
        }
        __syncthreads();   // B1: stats visible (also: all MFMA reads of xh done)

        // 5: combine halves, normalize, write hbuf[feat][row]
        #pragma unroll
        for (int r = 0; r < 4; ++r) {
            const int row = rg * 16 + q * 4 + r;
            float2 u0 = stat2[0][row], u1 = stat2[1][row];
            float mean = (u0.x + u1.x) * (1.0f / 128.0f);
            float var  = (u0.y + u1.y) * (1.0f / 128.0f) - mean * mean;
            float rs   = rsqrtf(var + EPSV);
            #pragma unroll
            for (int nt = 0; nt < 4; ++nt) {
                const int f = fbase + nt * 16 + l15;
                float hv = acc[nt][r] + bb[nt];
                hbuf[f * HB_STRIDE + row] = (hv - mean) * rs * lwv[nt] + lbv[nt];
            }
        }
        __syncthreads();   // B2: hbuf visible

        // 6: segmented scatter (batch sorted -> run-length reduce, then atomic)
        {
            const int f  = t & 127;
            const int r0 = (t >> 7) * 16;
            int seg = ibuf[r0];
            float a = 0.f;
            #pragma unroll
            for (int r = 0; r < 16; ++r) {
                const int sg = ibuf[r0 + r];
                const float v = hbuf[f * HB_STRIDE + r0 + r];
                if (sg != seg) {
                    atomicAdd(out + (size_t)seg * DIM + f, a);
                    a = 0.f;
                    seg = sg;
                }
                a += v;
            }
            atomicAdd(out + (size_t)seg * DIM + f, a);
        }
        __syncthreads();   // B3: scatter done before next tile reuses LDS
    }
}

__device__ __forceinline__ int lower_bound_seg(const int* __restrict__ batch, int v) {
    int lo = 0, hi = NROWS;
    while (lo < hi) {
        int m = (lo + hi) >> 1;
        if (batch[m] < v) lo = m + 1; else hi = m;
    }
    return lo;
}

__global__ __launch_bounds__(256)
void finalize_divide(float* __restrict__ out, const int* __restrict__ batch) {
    __shared__ float cnt[2];
    const int t = threadIdx.x;
    if (t < 2) {
        const int s = blockIdx.x * 2 + t;
        int c = lower_bound_seg(batch, s + 1) - lower_bound_seg(batch, s);
        cnt[t] = (float)max(c, 1);
    }
    __syncthreads();
    const size_t i = (size_t)blockIdx.x * 256 + t;
    out[i] = out[i] / cnt[t >> 7];
}

extern "C" void kernel_launch(void* const* d_in, const int* in_sizes, int n_in,
                              void* d_out, int out_size, void* d_ws, size_t ws_size,
                              hipStream_t stream) {
    const float* x     = (const float*)d_in[0];
    const int*   batch = (const int*)d_in[1];
    const float* W     = (const float*)d_in[2];
    const float* bias  = (const float*)d_in[3];
    const float* lnw   = (const float*)d_in[4];
    const float* lnb   = (const float*)d_in[5];
    float* out = (float*)d_out;

    hipMemsetAsync(out, 0, (size_t)out_size * sizeof(float), stream);
    fused_lin_ln_scatter<<<GRID1, 256, 0, stream>>>(x, batch, W, bias, lnw, lnb, out);
    finalize_divide<<<(NSEG * DIM) / 256, 256, 0, stream>>>(out, batch);
}

// Round 2
// 742.921 us; speedup vs baseline: 1.0247x; 1.0247x over previous
//
#include <hip/hip_runtime.h>
#include <hip/hip_bf16.h>

#define NROWS 1000000
#define DIM 128
#define NSEG 16384
#define TILE_M 32
#define NT (NROWS / TILE_M)      // 31250 tiles
#define XH_STRIDE 136            // bf16 elems per row (128 + 8 pad; 2-way bank alias = free)
#define GRID1 768                // 256 CU x 3 blocks resident (launch_bounds 256,3)
#define EPSV 1e-5f

typedef __bf16 bf16x8 __attribute__((ext_vector_type(8)));
typedef __bf16 bf16x4 __attribute__((ext_vector_type(4)));
typedef float  f32x4  __attribute__((ext_vector_type(4)));

// Per tile: 2 barriers only.
//   B0: xh + ibuf staged.  (then: snapshot seg-ids to regs, prefetch next tile, MFMA, stats)
//   B1: stat2 visible.     (then: normalize in regs, scatter via atomics, loop)
// Safety without B2/B3: xh(k+1) writes happen after B1(k), MFMA reads of xh(k) are
// pre-B1(k); ibuf(k) is snapshotted pre-B1(k); stat2(k+1) writes are post-B0(k+1)
// which all waves reach only after their stat2(k) reads.
__global__ __launch_bounds__(256, 3)
void fused_lin_ln_scatter(const float* __restrict__ x,
                          const int*   __restrict__ batch,
                          const float* __restrict__ W,
                          const float* __restrict__ bias,
                          const float* __restrict__ lnw,
                          const float* __restrict__ lnb,
                          float* __restrict__ out) {
    __shared__ __align__(16) __bf16 xh[TILE_M * XH_STRIDE];
    __shared__ float2 stat2[2][TILE_M];
    __shared__ int    ibuf[TILE_M];

    const int t    = threadIdx.x;
    const int wave = t >> 6;
    const int lane = t & 63;
    const int q    = lane >> 4;     // quad within wave
    const int l15  = lane & 15;
    const int rg   = wave >> 1;     // row group (0/1): rows rg*16..+16
    const int fh   = wave & 1;      // feature half (0/1)
    const int fbase = fh * 64;

    // ---- W fragments to registers (single bf16 pass; 64 VGPRs), once per block ----
    // lane needs W[n = fbase+nt*16+l15][k = ks*32 + q*8 + j]
    bf16x8 whf[4][4];
    #pragma unroll
    for (int nt = 0; nt < 4; ++nt) {
        const int f = fbase + nt * 16 + l15;
        #pragma unroll
        for (int ks = 0; ks < 4; ++ks) {
            const int k0 = ks * 32 + q * 8;
            const float4* wp = (const float4*)(W + f * DIM + k0);
            float4 a = wp[0], c = wp[1];
            float wv[8] = {a.x, a.y, a.z, a.w, c.x, c.y, c.z, c.w};
            bf16x8 hi;
            #pragma unroll
            for (int j = 0; j < 8; ++j) hi[j] = (__bf16)wv[j];
            whf[nt][ks] = hi;
        }
    }
    float bb[4], lwv[4], lbv[4];
    #pragma unroll
    for (int nt = 0; nt < 4; ++nt) {
        const int f = fbase + nt * 16 + l15;
        bb[nt]  = bias[f];
        lwv[nt] = lnw[f];
        lbv[nt] = lnb[f];
    }

    // ---- prologue: prefetch first tile into registers ----
    int it = blockIdx.x;
    float4 xr[4];
    int ibv = 0;
    {
        const float4* xp = (const float4*)(x + (size_t)it * TILE_M * DIM);
        #pragma unroll
        for (int j = 0; j < 4; ++j) xr[j] = xp[t + 256 * j];
        if (t < TILE_M) ibv = batch[it * TILE_M + t];
    }

    for (; it < NT; it += GRID1) {
        // 1: stage current tile (fp32 regs -> bf16 LDS) + segment ids
        #pragma unroll
        for (int j = 0; j < 4; ++j) {
            const int idx = t + 256 * j;
            const int row = idx >> 5;
            const int c4  = (idx & 31) * 4;
            float4 v = xr[j];
            bf16x4 pk = {(__bf16)v.x, (__bf16)v.y, (__bf16)v.z, (__bf16)v.w};
            *(bf16x4*)&xh[row * XH_STRIDE + c4] = pk;
        }
        if (t < TILE_M) ibuf[t] = ibv;
        __syncthreads();   // B0

        // 2: snapshot this wave's segment ids into registers (frees ibuf at B1)
        const int s_first = ibuf[rg * 16];
        const int s_last  = ibuf[rg * 16 + 15];
        int sgr[4];
        #pragma unroll
        for (int r = 0; r < 4; ++r) sgr[r] = ibuf[rg * 16 + q * 4 + r];

        // 3: prefetch next tile into registers (latency hides under MFMA/epilogue)
        const int itn = it + GRID1;
        if (itn < NT) {
            const float4* xp = (const float4*)(x + (size_t)itn * TILE_M * DIM);
            #pragma unroll
            for (int j = 0; j < 4; ++j) xr[j] = xp[t + 256 * j];
            if (t < TILE_M) ibv = batch[itn * TILE_M + t];
        }

        // 4: MFMA — 16 rows x 64 feats per wave, K=128, single bf16 pass
        //    bias pre-folded into accumulator (feature == col == l15-indexed)
        f32x4 acc[4];
        #pragma unroll
        for (int nt = 0; nt < 4; ++nt)
            acc[nt] = (f32x4){bb[nt], bb[nt], bb[nt], bb[nt]};
        const int row_l = rg * 16 + l15;
        #pragma unroll
        for (int ks = 0; ks < 4; ++ks) {
            bf16x8 af = *(const bf16x8*)&xh[row_l * XH_STRIDE + ks * 32 + q * 8];
            #pragma unroll
            for (int nt = 0; nt < 4; ++nt)
                acc[nt] = __builtin_amdgcn_mfma_f32_16x16x32_bf16(af, whf[nt][ks], acc[nt], 0, 0, 0);
        }

        // 5: row stats over this wave's 64 features (16-lane butterfly)
        #pragma unroll
        for (int r = 0; r < 4; ++r) {
            float s  = acc[0][r] + acc[1][r] + acc[2][r] + acc[3][r];
            float sq = acc[0][r] * acc[0][r] + acc[1][r] * acc[1][r]
                     + acc[2][r] * acc[2][r] + acc[3][r] * acc[3][r];
            #pragma unroll
            for (int m = 1; m < 16; m <<= 1) {
                s  += __shfl_xor(s,  m, 64);
                sq += __shfl_xor(sq, m, 64);
            }
            if (l15 == 0)
                stat2[fh][rg * 16 + q * 4 + r] = make_float2(s, sq);
        }
        __syncthreads();   // B1

        // 6: normalize in registers
        float nv[4][4];    // [nt][r]
        #pragma unroll
        for (int r = 0; r < 4; ++r) {
            const int row = rg * 16 + q * 4 + r;
            float2 u0 = stat2[0][row], u1 = stat2[1][row];
            float mean = (u0.x + u1.x) * (1.0f / 128.0f);
            float var  = (u0.y + u1.y) * (1.0f / 128.0f) - mean * mean;
            float rs   = rsqrtf(var + EPSV);
            #pragma unroll
            for (int nt = 0; nt < 4; ++nt)
                nv[nt][r] = (acc[nt][r] - mean) * rs * lwv[nt] + lbv[nt];
        }

        // 7: segmented scatter from registers.
        // Fast path (16-row window segment-uniform, p~0.75): reduce across q via
        // shfl_xor(16|32), one coalesced 64B atomic per nt by quarter of lanes.
        if (s_first == s_last) {
            #pragma unroll
            for (int nt = 0; nt < 4; ++nt) {
                float v = nv[nt][0] + nv[nt][1] + nv[nt][2] + nv[nt][3];
                v += __shfl_xor(v, 16, 64);
                v += __shfl_xor(v, 32, 64);
                if (q == 0)
                    atomicAdd(out + (size_t)s_first * DIM + fbase + nt * 16 + l15, v);
            }
        } else {
            #pragma unroll
            for (int nt = 0; nt < 4; ++nt) {
                const int f = fbase + nt * 16 + l15;
                float a = nv[nt][0];
                #pragma unroll
                for (int r = 1; r < 4; ++r) {
                    if (sgr[r] != sgr[r - 1]) {
                        atomicAdd(out + (size_t)sgr[r - 1] * DIM + f, a);
                        a = 0.f;
                    }
                    a += nv[nt][r];
                }
                atomicAdd(out + (size_t)sgr[3] * DIM + f, a);
            }
        }
        // no barrier: next staging is safe per the invariants above
    }
}

__device__ __forceinline__ int lower_bound_seg(const int* __restrict__ batch, int v) {
    int lo = 0, hi = NROWS;
    while (lo < hi) {
        int m = (lo + hi) >> 1;
        if (batch[m] < v) lo = m + 1; else hi = m;
    }
    return lo;
}

__global__ __launch_bounds__(256)
void finalize_divide(float* __restrict__ out, const int* __restrict__ batch) {
    __shared__ float cnt[2];
    const int t = threadIdx.x;
    if (t < 2) {
        const int s = blockIdx.x * 2 + t;
        int c = lower_bound_seg(batch, s + 1) - lower_bound_seg(batch, s);
        cnt[t] = (float)max(c, 1);
    }
    __syncthreads();
    const size_t i = (size_t)blockIdx.x * 256 + t;
    out[i] = out[i] / cnt[t >> 7];
}

extern "C" void kernel_launch(void* const* d_in, const int* in_sizes, int n_in,
                              void* d_out, int out_size, void* d_ws, size_t ws_size,
                              hipStream_t stream) {
    const float* x     = (const float*)d_in[0];
    const int*   batch = (const int*)d_in[1];
    const float* W     = (const float*)d_in[2];
    const float* bias  = (const float*)d_in[3];
    const float* lnw   = (const float*)d_in[4];
    const float* lnb   = (const float*)d_in[5];
    float* out = (float*)d_out;

    hipMemsetAsync(out, 0, (size_t)out_size * sizeof(float), stream);
    fused_lin_ln_scatter<<<GRID1, 256, 0, stream>>>(x, batch, W, bias, lnw, lnb, out);
    finalize_divide<<<(NSEG * DIM) / 256, 256, 0, stream>>>(out, batch);
}